// Round 1
// baseline (1243.238 us; speedup 1.0000x reference)
//
#include <hip/hip_runtime.h>

#define N_NODES 50000
#define N_EDGES 800000
// feature dims
#define F_NODE 128
#define F_EDGE 16

// --- scatter: acc[dst[e]*128 + j] += x[src[e]*128 + j] ---------------------
// 128 threads per edge (2 edges per 256-block). Gather load and atomic
// destination addresses are both fully coalesced (consecutive j).
__global__ __launch_bounds__(256) void scatter_feat128(
    const float* __restrict__ x,
    const int*   __restrict__ src,
    const int*   __restrict__ dst,
    float*       __restrict__ acc)
{
    long long gid = (long long)blockIdx.x * 256 + threadIdx.x;
    int e = (int)(gid >> 7);
    int j = (int)(gid & 127);
    if (e >= N_EDGES) return;
    int s = src[e];
    int d = dst[e];
    atomicAdd(&acc[(long long)d * F_NODE + j], x[(long long)s * F_NODE + j]);
}

// --- scatter: ea[dst[e]*16 + j] += edge_attr[e*16 + j] ---------------------
__global__ __launch_bounds__(256) void scatter_feat16(
    const float* __restrict__ eattr,
    const int*   __restrict__ dst,
    float*       __restrict__ acc)
{
    long long gid = (long long)blockIdx.x * 256 + threadIdx.x;
    int e = (int)(gid >> 4);
    int j = (int)(gid & 15);
    if (e >= N_EDGES) return;
    int d = dst[e];
    atomicAdd(&acc[(long long)d * F_EDGE + j], eattr[(long long)e * F_EDGE + j]);
}

// --- per-node matmul: out[n,j] = f( xa[n,:]@W[0:128,j] + ea[n,:]@W[128:144,j] + b[j] )
// W is (144,128) row-major. One thread per (n,j); xa row loads are
// wave-uniform (cached), W column loads are coalesced across lanes and fully
// L1/L2 resident (73.7 KB total).
__global__ __launch_bounds__(256) void layer_mm(
    const float* __restrict__ xa,
    const float* __restrict__ ea,
    const float* __restrict__ W,
    const float* __restrict__ b,
    float*       __restrict__ out,
    int do_relu)
{
    long long gid = (long long)blockIdx.x * 256 + threadIdx.x;
    int n = (int)(gid >> 7);
    int j = (int)(gid & 127);
    if (n >= N_NODES) return;
    const float* xr = xa + (long long)n * F_NODE;
    const float* er = ea + (long long)n * F_EDGE;
    float acc = b[j];
    #pragma unroll 8
    for (int k = 0; k < F_NODE; ++k)
        acc = fmaf(xr[k], W[k * 128 + j], acc);
    #pragma unroll
    for (int k = 0; k < F_EDGE; ++k)
        acc = fmaf(er[k], W[(F_NODE + k) * 128 + j], acc);
    if (do_relu) acc = fmaxf(acc, 0.0f);
    out[(long long)n * 128 + j] = acc;
}

extern "C" void kernel_launch(void* const* d_in, const int* in_sizes, int n_in,
                              void* d_out, int out_size, void* d_ws, size_t ws_size,
                              hipStream_t stream) {
    const float* x     = (const float*)d_in[0];   // (50000,128)
    const int*   eidx  = (const int*)  d_in[1];   // (2,800000)
    const float* eattr = (const float*)d_in[2];   // (800000,16)
    const float* W1    = (const float*)d_in[3];   // (144,128)
    const float* b1    = (const float*)d_in[4];   // (128,)
    const float* W2    = (const float*)d_in[5];   // (144,128)
    const float* b2    = (const float*)d_in[6];   // (128,)
    float* out = (float*)d_out;                   // (50000,128)

    const int* src = eidx;
    const int* dst = eidx + N_EDGES;

    // workspace layout: xa (50000*128 f32) | ea (50000*16 f32)  = 28.8 MB
    float* xa = (float*)d_ws;
    float* ea = xa + (long long)N_NODES * F_NODE;

    // zero accumulators (xa and ea are contiguous)
    hipMemsetAsync(xa, 0, (size_t)N_NODES * (F_NODE + F_EDGE) * sizeof(float), stream);

    // aggregate raw node features and edge attrs per destination
    {
        long long threads = (long long)N_EDGES * F_NODE;
        scatter_feat128<<<(int)((threads + 255) / 256), 256, 0, stream>>>(x, src, dst, xa);
    }
    {
        long long threads = (long long)N_EDGES * F_EDGE;
        scatter_feat16<<<(int)((threads + 255) / 256), 256, 0, stream>>>(eattr, dst, ea);
    }

    // layer 1: h = relu(xa @ W1x + ea @ W1e + b1) -> stored in d_out (scratch)
    {
        long long threads = (long long)N_NODES * 128;
        layer_mm<<<(int)((threads + 255) / 256), 256, 0, stream>>>(xa, ea, W1, b1, out, 1);
    }

    // re-zero xa, aggregate h per destination
    hipMemsetAsync(xa, 0, (size_t)N_NODES * F_NODE * sizeof(float), stream);
    {
        long long threads = (long long)N_EDGES * F_NODE;
        scatter_feat128<<<(int)((threads + 255) / 256), 256, 0, stream>>>(out, src, dst, xa);
    }

    // layer 2: out = xa @ W2x + ea @ W2e + b2 (layer_mm never reads `out`,
    // so overwriting the h scratch in-place is safe)
    {
        long long threads = (long long)N_NODES * 128;
        layer_mm<<<(int)((threads + 255) / 256), 256, 0, stream>>>(xa, ea, W2, b2, out, 0);
    }
}

// Round 2
// 428.850 us; speedup vs baseline: 2.8990x; 2.8990x over previous
//
#include <hip/hip_runtime.h>

#define N_NODES 50000
#define N_EDGES 800000
#define F_NODE 128
#define F_EDGE 16

#define SCAN_B 256
#define NB1 ((N_NODES + SCAN_B - 1) / SCAN_B)   // 196 blocks

// ---------------------------------------------------------------------------
// CSR build: histogram of dst
__global__ __launch_bounds__(256) void hist_dst(const int* __restrict__ dst,
                                                int* __restrict__ deg) {
    int e = blockIdx.x * 256 + threadIdx.x;
    if (e >= N_EDGES) return;
    atomicAdd(&deg[dst[e]], 1);
}

// block-level exclusive scan (Hillis-Steele in LDS), per-block sums out
__global__ __launch_bounds__(256) void scan1(const int* __restrict__ deg,
                                             int* __restrict__ rs,
                                             int* __restrict__ bsum) {
    __shared__ int sh[SCAN_B];
    int i = blockIdx.x * SCAN_B + threadIdx.x;
    int v = (i < N_NODES) ? deg[i] : 0;
    sh[threadIdx.x] = v;
    __syncthreads();
    for (int off = 1; off < SCAN_B; off <<= 1) {
        int t = (threadIdx.x >= off) ? sh[threadIdx.x - off] : 0;
        __syncthreads();
        sh[threadIdx.x] += t;
        __syncthreads();
    }
    if (i < N_NODES) rs[i] = sh[threadIdx.x] - v;      // exclusive within block
    if (threadIdx.x == SCAN_B - 1) bsum[blockIdx.x] = sh[threadIdx.x];
}

__global__ __launch_bounds__(256) void scan2(const int* __restrict__ bsum,
                                             int* __restrict__ boff) {
    __shared__ int sh[SCAN_B];
    int v = (threadIdx.x < NB1) ? bsum[threadIdx.x] : 0;
    sh[threadIdx.x] = v;
    __syncthreads();
    for (int off = 1; off < SCAN_B; off <<= 1) {
        int t = (threadIdx.x >= off) ? sh[threadIdx.x - off] : 0;
        __syncthreads();
        sh[threadIdx.x] += t;
        __syncthreads();
    }
    boff[threadIdx.x] = sh[threadIdx.x] - v;           // exclusive block offsets
}

__global__ __launch_bounds__(256) void scan3(int* __restrict__ rs,
                                             const int* __restrict__ boff) {
    int i = blockIdx.x * 256 + threadIdx.x;
    if (i < N_NODES) rs[i] += boff[i >> 8];
    if (i == 0) rs[N_NODES] = N_EDGES;
}

__global__ __launch_bounds__(256) void csr_fill(const int* __restrict__ src,
                                                const int* __restrict__ dst,
                                                const int* __restrict__ rs,
                                                int* __restrict__ cur,
                                                int* __restrict__ csr_src,
                                                int* __restrict__ csr_eid) {
    int e = blockIdx.x * 256 + threadIdx.x;
    if (e >= N_EDGES) return;
    int d = dst[e];
    int pos = rs[d] + atomicAdd(&cur[d], 1);
    csr_src[pos] = src[e];
    csr_eid[pos] = e;
}

// ---------------------------------------------------------------------------
// aggregation: xa[n,:] = sum over in-edges of x[src,:]   (32 thr/node, float4)
__global__ __launch_bounds__(256) void agg_feat128(const float* __restrict__ x,
                                                   const int* __restrict__ rs,
                                                   const int* __restrict__ csr_src,
                                                   float* __restrict__ xa) {
    int gid = blockIdx.x * 256 + threadIdx.x;
    int n = gid >> 5;
    int q = (gid & 31) << 2;          // float offset 0..124
    if (n >= N_NODES) return;
    int beg = rs[n], end = rs[n + 1];
    float4 acc = make_float4(0.f, 0.f, 0.f, 0.f);
    for (int i = beg; i < end; ++i) {
        int s = csr_src[i];
        float4 v = *(const float4*)(x + (size_t)s * F_NODE + q);
        acc.x += v.x; acc.y += v.y; acc.z += v.z; acc.w += v.w;
    }
    *(float4*)(xa + (size_t)n * F_NODE + q) = acc;
}

// aggregation of edge attrs: eagg[n,:] = sum eattr[eid,:]   (16 thr/node)
__global__ __launch_bounds__(256) void agg_feat16(const float* __restrict__ eattr,
                                                  const int* __restrict__ rs,
                                                  const int* __restrict__ csr_eid,
                                                  float* __restrict__ eagg) {
    int gid = blockIdx.x * 256 + threadIdx.x;
    int n = gid >> 4;
    int j = gid & 15;
    if (n >= N_NODES) return;
    int beg = rs[n], end = rs[n + 1];
    float acc = 0.f;
    for (int i = beg; i < end; ++i) {
        int eid = csr_eid[i];
        acc += eattr[(size_t)eid * F_EDGE + j];
    }
    eagg[(size_t)n * F_EDGE + j] = acc;
}

// ---------------------------------------------------------------------------
// tiled fp32 GEMM: out(50000x128) = [xa|eagg](50000x144) @ W(144x128) + b
// BM=64, BN=128, BK=16; 256 threads; 4x8 register tile per thread.
#define BM 64
#define BK 16
#define LDA (BM + 4)     // pad to break bank aliasing, keeps 16B row align
#define LDB (128 + 4)

__global__ __launch_bounds__(256) void layer_gemm(
    const float* __restrict__ xa,     // (N,128)
    const float* __restrict__ eagg,   // (N,16)
    const float* __restrict__ W,      // (144,128) row-major
    const float* __restrict__ bias,   // (128,)
    float* __restrict__ out,          // (N,128)
    int do_relu)
{
    __shared__ float As[BK][LDA];     // As[k][m]
    __shared__ float Bs[BK][LDB];     // Bs[k][j]
    const int tid = threadIdx.x;
    const int bm = blockIdx.x * BM;

    const int tcol = (tid & 15) * 8;          // output col base
    const int trow = (tid >> 4) * 4;          // output row base (within tile)

    // A-tile loader mapping: thread -> (row lm, k-quad lk), contiguous 16B
    const int lm = tid >> 2;                  // 0..63
    const int lk = (tid & 3) * 4;             // 0,4,8,12
    // B-tile loader mapping
    const int bk = tid >> 4;                  // 0..15
    const int bj = (tid & 15) * 8;            // 0..120

    const int row = bm + lm;
    const bool rowok = row < N_NODES;

    float acc[4][8];
    #pragma unroll
    for (int i = 0; i < 4; ++i)
        #pragma unroll
        for (int j = 0; j < 8; ++j) acc[i][j] = 0.f;

    for (int k0 = 0; k0 < 144; k0 += BK) {
        float4 av = make_float4(0.f, 0.f, 0.f, 0.f);
        if (rowok) {
            if (k0 < F_NODE)
                av = *(const float4*)(xa + (size_t)row * F_NODE + k0 + lk);
            else
                av = *(const float4*)(eagg + (size_t)row * F_EDGE + lk);
        }
        As[lk + 0][lm] = av.x;
        As[lk + 1][lm] = av.y;
        As[lk + 2][lm] = av.z;
        As[lk + 3][lm] = av.w;

        const float4 b0 = *(const float4*)(W + (size_t)(k0 + bk) * 128 + bj);
        const float4 b1 = *(const float4*)(W + (size_t)(k0 + bk) * 128 + bj + 4);
        *(float4*)(&Bs[bk][bj])     = b0;
        *(float4*)(&Bs[bk][bj + 4]) = b1;
        __syncthreads();

        #pragma unroll
        for (int k = 0; k < BK; ++k) {
            float a0 = As[k][trow + 0];
            float a1 = As[k][trow + 1];
            float a2 = As[k][trow + 2];
            float a3 = As[k][trow + 3];
            float bv[8];
            #pragma unroll
            for (int j = 0; j < 8; ++j) bv[j] = Bs[k][tcol + j];
            #pragma unroll
            for (int j = 0; j < 8; ++j) {
                acc[0][j] = fmaf(a0, bv[j], acc[0][j]);
                acc[1][j] = fmaf(a1, bv[j], acc[1][j]);
                acc[2][j] = fmaf(a2, bv[j], acc[2][j]);
                acc[3][j] = fmaf(a3, bv[j], acc[3][j]);
            }
        }
        __syncthreads();
    }

    // epilogue: bias (+relu), vector store
    float4 bb0 = *(const float4*)(bias + tcol);
    float4 bb1 = *(const float4*)(bias + tcol + 4);
    #pragma unroll
    for (int i = 0; i < 4; ++i) {
        int r = bm + trow + i;
        if (r >= N_NODES) break;
        float v[8];
        v[0] = acc[i][0] + bb0.x; v[1] = acc[i][1] + bb0.y;
        v[2] = acc[i][2] + bb0.z; v[3] = acc[i][3] + bb0.w;
        v[4] = acc[i][4] + bb1.x; v[5] = acc[i][5] + bb1.y;
        v[6] = acc[i][6] + bb1.z; v[7] = acc[i][7] + bb1.w;
        if (do_relu) {
            #pragma unroll
            for (int j = 0; j < 8; ++j) v[j] = fmaxf(v[j], 0.f);
        }
        float4 s0 = make_float4(v[0], v[1], v[2], v[3]);
        float4 s1 = make_float4(v[4], v[5], v[6], v[7]);
        *(float4*)(out + (size_t)r * 128 + tcol)     = s0;
        *(float4*)(out + (size_t)r * 128 + tcol + 4) = s1;
    }
}

// ---------------------------------------------------------------------------
extern "C" void kernel_launch(void* const* d_in, const int* in_sizes, int n_in,
                              void* d_out, int out_size, void* d_ws, size_t ws_size,
                              hipStream_t stream) {
    const float* x     = (const float*)d_in[0];   // (50000,128)
    const int*   eidx  = (const int*)  d_in[1];   // (2,800000)
    const float* eattr = (const float*)d_in[2];   // (800000,16)
    const float* W1    = (const float*)d_in[3];   // (144,128)
    const float* b1    = (const float*)d_in[4];
    const float* W2    = (const float*)d_in[5];   // (144,128)
    const float* b2    = (const float*)d_in[6];
    float* out = (float*)d_out;                   // (50000,128)

    const int* srcv = eidx;
    const int* dstv = eidx + N_EDGES;

    // workspace layout (all 4B-aligned; base is 16B-aligned)
    char* p = (char*)d_ws;
    float* xa       = (float*)p;                 p += (size_t)N_NODES * F_NODE * 4;  // 25.6 MB
    float* eagg     = (float*)p;                 p += (size_t)N_NODES * F_EDGE * 4;  //  3.2 MB
    int*   rs       = (int*)p;                   p += (size_t)(N_NODES + 1) * 4;
    p = (char*)(((uintptr_t)p + 15) & ~(uintptr_t)15);
    int*   deg      = (int*)p;                   p += (size_t)N_NODES * 4;
    int*   cur      = (int*)p;                   p += (size_t)N_NODES * 4;
    int*   bsum     = (int*)p;                   p += 256 * 4;
    int*   boff     = (int*)p;                   p += 256 * 4;
    int*   csr_src  = (int*)p;                   p += (size_t)N_EDGES * 4;
    int*   csr_eid  = (int*)p;                   /* total ~35.9 MB */

    // zero histogram + cursors (contiguous)
    hipMemsetAsync(deg, 0, (size_t)N_NODES * 2 * sizeof(int), stream);

    // ---- CSR build (by dst) ----
    hist_dst<<<(N_EDGES + 255) / 256, 256, 0, stream>>>(dstv, deg);
    scan1<<<NB1, SCAN_B, 0, stream>>>(deg, rs, bsum);
    scan2<<<1, SCAN_B, 0, stream>>>(bsum, boff);
    scan3<<<NB1, SCAN_B, 0, stream>>>(rs, boff);
    csr_fill<<<(N_EDGES + 255) / 256, 256, 0, stream>>>(srcv, dstv, rs, cur,
                                                        csr_src, csr_eid);

    // ---- aggregate edge attrs once (shared by both layers) ----
    agg_feat16<<<(N_NODES * 16 + 255) / 256, 256, 0, stream>>>(eattr, rs, csr_eid, eagg);

    // ---- layer 1 ----
    agg_feat128<<<(N_NODES * 32 + 255) / 256, 256, 0, stream>>>(x, rs, csr_src, xa);
    layer_gemm<<<(N_NODES + BM - 1) / BM, 256, 0, stream>>>(xa, eagg, W1, b1, out, 1);

    // ---- layer 2 (h lives in d_out; gemm never reads out before writing) ----
    agg_feat128<<<(N_NODES * 32 + 255) / 256, 256, 0, stream>>>(out, rs, csr_src, xa);
    layer_gemm<<<(N_NODES + BM - 1) / BM, 256, 0, stream>>>(xa, eagg, W2, b2, out, 0);
}

// Round 3
// 382.629 us; speedup vs baseline: 3.2492x; 1.1208x over previous
//
#include <hip/hip_runtime.h>

#define N_NODES 50000
#define N_EDGES 800000
#define F_NODE 128
#define F_EDGE 16

#define SCAN_B 256
#define NB1 ((N_NODES + SCAN_B - 1) / SCAN_B)   // 196 blocks

// ---------------- bf16 helpers (bf16 = top 16 bits of fp32, RNE) -----------
__device__ __forceinline__ unsigned int bf16_rn(float f) {
    unsigned int u = __float_as_uint(f);
    unsigned int r = ((u >> 16) & 1u) + 0x7fffu;
    return (u + r) >> 16;
}
__device__ __forceinline__ unsigned int pack_bf16(float a, float b) {
    return bf16_rn(a) | (bf16_rn(b) << 16);
}
__device__ __forceinline__ float bf_lo(unsigned int u) { return __uint_as_float(u << 16); }
__device__ __forceinline__ float bf_hi(unsigned int u) { return __uint_as_float(u & 0xffff0000u); }

// ---------------- convert x (N,128 fp32) -> packed bf16 pairs --------------
__global__ __launch_bounds__(256) void f32_to_bf16(const float4* __restrict__ in,
                                                   uint2* __restrict__ outp,
                                                   int n4) {
    int i = blockIdx.x * 256 + threadIdx.x;
    if (i >= n4) return;
    float4 v = in[i];
    uint2 o;
    o.x = pack_bf16(v.x, v.y);
    o.y = pack_bf16(v.z, v.w);
    outp[i] = o;
}

// ---------------- CSR build ------------------------------------------------
__global__ __launch_bounds__(256) void hist_dst(const int* __restrict__ dst,
                                                int* __restrict__ deg) {
    int e = blockIdx.x * 256 + threadIdx.x;
    if (e >= N_EDGES) return;
    atomicAdd(&deg[dst[e]], 1);
}

__global__ __launch_bounds__(256) void scan1(const int* __restrict__ deg,
                                             int* __restrict__ rs,
                                             int* __restrict__ bsum) {
    __shared__ int sh[SCAN_B];
    int i = blockIdx.x * SCAN_B + threadIdx.x;
    int v = (i < N_NODES) ? deg[i] : 0;
    sh[threadIdx.x] = v;
    __syncthreads();
    for (int off = 1; off < SCAN_B; off <<= 1) {
        int t = (threadIdx.x >= off) ? sh[threadIdx.x - off] : 0;
        __syncthreads();
        sh[threadIdx.x] += t;
        __syncthreads();
    }
    if (i < N_NODES) rs[i] = sh[threadIdx.x] - v;
    if (threadIdx.x == SCAN_B - 1) bsum[blockIdx.x] = sh[threadIdx.x];
}

__global__ __launch_bounds__(256) void scan2(const int* __restrict__ bsum,
                                             int* __restrict__ boff) {
    __shared__ int sh[SCAN_B];
    int v = (threadIdx.x < NB1) ? bsum[threadIdx.x] : 0;
    sh[threadIdx.x] = v;
    __syncthreads();
    for (int off = 1; off < SCAN_B; off <<= 1) {
        int t = (threadIdx.x >= off) ? sh[threadIdx.x - off] : 0;
        __syncthreads();
        sh[threadIdx.x] += t;
        __syncthreads();
    }
    boff[threadIdx.x] = sh[threadIdx.x] - v;
}

__global__ __launch_bounds__(256) void scan3(int* __restrict__ rs,
                                             const int* __restrict__ boff) {
    int i = blockIdx.x * 256 + threadIdx.x;
    if (i < N_NODES) rs[i] += boff[i >> 8];
    if (i == 0) rs[N_NODES] = N_EDGES;
}

__global__ __launch_bounds__(256) void csr_fill(const int* __restrict__ src,
                                                const int* __restrict__ dst,
                                                const int* __restrict__ rs,
                                                int* __restrict__ cur,
                                                int2* __restrict__ csr) {
    int e = blockIdx.x * 256 + threadIdx.x;
    if (e >= N_EDGES) return;
    int d = dst[e];
    int pos = rs[d] + atomicAdd(&cur[d], 1);
    csr[pos] = make_int2(src[e], e);
}

// ---------------- node-feature aggregation (bf16 source) -------------------
// one wave per node; 64 lanes x 4B (2 bf16) = full 256B row; 4-edge unroll.
__global__ __launch_bounds__(256) void agg128_bf16(const unsigned int* __restrict__ xb,
                                                   const int* __restrict__ rs,
                                                   const int2* __restrict__ csr,
                                                   float* __restrict__ xa) {
    int gid = blockIdx.x * 256 + threadIdx.x;
    int n = gid >> 6;
    int lane = threadIdx.x & 63;
    if (n >= N_NODES) return;
    int beg = rs[n], end = rs[n + 1];
    float a0 = 0.f, a1 = 0.f;
    int i = beg;
    for (; i + 4 <= end; i += 4) {
        int s0 = csr[i].x, s1 = csr[i + 1].x, s2 = csr[i + 2].x, s3 = csr[i + 3].x;
        unsigned int u0 = xb[(size_t)s0 * 64 + lane];
        unsigned int u1 = xb[(size_t)s1 * 64 + lane];
        unsigned int u2 = xb[(size_t)s2 * 64 + lane];
        unsigned int u3 = xb[(size_t)s3 * 64 + lane];
        a0 += bf_lo(u0) + bf_lo(u1) + bf_lo(u2) + bf_lo(u3);
        a1 += bf_hi(u0) + bf_hi(u1) + bf_hi(u2) + bf_hi(u3);
    }
    for (; i < end; ++i) {
        unsigned int u = xb[(size_t)csr[i].x * 64 + lane];
        a0 += bf_lo(u);
        a1 += bf_hi(u);
    }
    *(float2*)(xa + (size_t)n * F_NODE + lane * 2) = make_float2(a0, a1);
}

// ---------------- edge-attr aggregation ------------------------------------
// one wave per node; 4 subgroups x 16 lanes take every 4th edge; butterfly.
__global__ __launch_bounds__(256) void agg_feat16(const float* __restrict__ eattr,
                                                  const int* __restrict__ rs,
                                                  const int2* __restrict__ csr,
                                                  float* __restrict__ eagg) {
    int gid = blockIdx.x * 256 + threadIdx.x;
    int n = gid >> 6;
    int lane = threadIdx.x & 63;
    int sub = lane >> 4;
    int j = lane & 15;
    if (n >= N_NODES) return;
    int beg = rs[n], end = rs[n + 1];
    float acc = 0.f;
    for (int i = beg + sub; i < end; i += 4) {
        int eid = csr[i].y;
        acc += eattr[(size_t)eid * F_EDGE + j];
    }
    acc += __shfl_xor(acc, 16, 64);
    acc += __shfl_xor(acc, 32, 64);
    if (sub == 0) eagg[(size_t)n * F_EDGE + j] = acc;
}

// ---------------- tiled fp32 GEMM ------------------------------------------
// out = [xa|eagg](N x 144) @ W(144x128) + b; optional fused-relu bf16 output.
// xa may alias out_f32 (d_out): each block reads its rows before writing them.
#define BM 64
#define BK 16
#define LDA (BM + 4)
#define LDB (128 + 4)

__global__ __launch_bounds__(256) void layer_gemm(
    const float* xa,
    const float* __restrict__ eagg,
    const float* __restrict__ W,
    const float* __restrict__ bias,
    float* out_f32,
    unsigned int* __restrict__ out_bf,
    int do_relu, int out_bf16)
{
    __shared__ float As[BK][LDA];
    __shared__ float Bs[BK][LDB];
    const int tid = threadIdx.x;
    const int bm = blockIdx.x * BM;

    const int tcol = (tid & 15) * 8;
    const int trow = (tid >> 4) * 4;

    const int lm = tid >> 2;
    const int lk = (tid & 3) * 4;
    const int bk = tid >> 4;
    const int bj = (tid & 15) * 8;

    const int row = bm + lm;
    const bool rowok = row < N_NODES;

    float acc[4][8];
    #pragma unroll
    for (int i = 0; i < 4; ++i)
        #pragma unroll
        for (int j = 0; j < 8; ++j) acc[i][j] = 0.f;

    for (int k0 = 0; k0 < 144; k0 += BK) {
        float4 av = make_float4(0.f, 0.f, 0.f, 0.f);
        if (rowok) {
            if (k0 < F_NODE)
                av = *(const float4*)(xa + (size_t)row * F_NODE + k0 + lk);
            else
                av = *(const float4*)(eagg + (size_t)row * F_EDGE + lk);
        }
        As[lk + 0][lm] = av.x;
        As[lk + 1][lm] = av.y;
        As[lk + 2][lm] = av.z;
        As[lk + 3][lm] = av.w;

        const float4 b0 = *(const float4*)(W + (size_t)(k0 + bk) * 128 + bj);
        const float4 b1 = *(const float4*)(W + (size_t)(k0 + bk) * 128 + bj + 4);
        *(float4*)(&Bs[bk][bj])     = b0;
        *(float4*)(&Bs[bk][bj + 4]) = b1;
        __syncthreads();

        #pragma unroll
        for (int k = 0; k < BK; ++k) {
            float a0 = As[k][trow + 0];
            float a1 = As[k][trow + 1];
            float a2 = As[k][trow + 2];
            float a3 = As[k][trow + 3];
            float bv[8];
            #pragma unroll
            for (int j = 0; j < 8; ++j) bv[j] = Bs[k][tcol + j];
            #pragma unroll
            for (int j = 0; j < 8; ++j) {
                acc[0][j] = fmaf(a0, bv[j], acc[0][j]);
                acc[1][j] = fmaf(a1, bv[j], acc[1][j]);
                acc[2][j] = fmaf(a2, bv[j], acc[2][j]);
                acc[3][j] = fmaf(a3, bv[j], acc[3][j]);
            }
        }
        __syncthreads();
    }

    float4 bb0 = *(const float4*)(bias + tcol);
    float4 bb1 = *(const float4*)(bias + tcol + 4);
    #pragma unroll
    for (int i = 0; i < 4; ++i) {
        int r = bm + trow + i;
        if (r >= N_NODES) break;
        float v[8];
        v[0] = acc[i][0] + bb0.x; v[1] = acc[i][1] + bb0.y;
        v[2] = acc[i][2] + bb0.z; v[3] = acc[i][3] + bb0.w;
        v[4] = acc[i][4] + bb1.x; v[5] = acc[i][5] + bb1.y;
        v[6] = acc[i][6] + bb1.z; v[7] = acc[i][7] + bb1.w;
        if (do_relu) {
            #pragma unroll
            for (int j = 0; j < 8; ++j) v[j] = fmaxf(v[j], 0.f);
        }
        if (out_bf16) {
            uint4 s;
            s.x = pack_bf16(v[0], v[1]);
            s.y = pack_bf16(v[2], v[3]);
            s.z = pack_bf16(v[4], v[5]);
            s.w = pack_bf16(v[6], v[7]);
            *(uint4*)(out_bf + (size_t)r * 64 + tcol / 2) = s;
        } else {
            *(float4*)(out_f32 + (size_t)r * 128 + tcol)     = make_float4(v[0], v[1], v[2], v[3]);
            *(float4*)(out_f32 + (size_t)r * 128 + tcol + 4) = make_float4(v[4], v[5], v[6], v[7]);
        }
    }
}

// ---------------------------------------------------------------------------
extern "C" void kernel_launch(void* const* d_in, const int* in_sizes, int n_in,
                              void* d_out, int out_size, void* d_ws, size_t ws_size,
                              hipStream_t stream) {
    const float* x     = (const float*)d_in[0];   // (50000,128)
    const int*   eidx  = (const int*)  d_in[1];   // (2,800000)
    const float* eattr = (const float*)d_in[2];   // (800000,16)
    const float* W1    = (const float*)d_in[3];   // (144,128)
    const float* b1    = (const float*)d_in[4];
    const float* W2    = (const float*)d_in[5];   // (144,128)
    const float* b2    = (const float*)d_in[6];
    float* out = (float*)d_out;                   // (50000,128)

    const int* srcv = eidx;
    const int* dstv = eidx + N_EDGES;

    // ws layout (~23 MB)
    char* p = (char*)d_ws;
    unsigned int* xbhb = (unsigned int*)p;  p += (size_t)N_NODES * 64 * 4;      // 12.8 MB (xb, later hb)
    float* eagg        = (float*)p;         p += (size_t)N_NODES * F_EDGE * 4;  //  3.2 MB
    int2*  csr         = (int2*)p;          p += (size_t)N_EDGES * 8;           //  6.4 MB
    int*   rs          = (int*)p;           p += (size_t)(N_NODES + 1) * 4;
    int*   deg         = (int*)p;           p += (size_t)N_NODES * 4;
    int*   cur         = (int*)p;           p += (size_t)N_NODES * 4;
    int*   bsum        = (int*)p;           p += 256 * 4;
    int*   boff        = (int*)p;

    float* xa = out;   // aggregated features live in d_out (see layer_gemm note)

    hipMemsetAsync(deg, 0, (size_t)N_NODES * 2 * sizeof(int), stream);

    f32_to_bf16<<<(N_NODES * 32 + 255) / 256, 256, 0, stream>>>(
        (const float4*)x, (uint2*)xbhb, N_NODES * 32);

    hist_dst<<<(N_EDGES + 255) / 256, 256, 0, stream>>>(dstv, deg);
    scan1<<<NB1, SCAN_B, 0, stream>>>(deg, rs, bsum);
    scan2<<<1, SCAN_B, 0, stream>>>(bsum, boff);
    scan3<<<NB1, SCAN_B, 0, stream>>>(rs, boff);
    csr_fill<<<(N_EDGES + 255) / 256, 256, 0, stream>>>(srcv, dstv, rs, cur, csr);

    agg_feat16<<<(N_NODES * 64 + 255) / 256, 256, 0, stream>>>(eattr, rs, csr, eagg);

    // layer 1
    agg128_bf16<<<(N_NODES * 64 + 255) / 256, 256, 0, stream>>>(xbhb, rs, csr, xa);
    layer_gemm<<<(N_NODES + BM - 1) / BM, 256, 0, stream>>>(
        xa, eagg, W1, b1, (float*)nullptr, xbhb, 1, 1);

    // layer 2
    agg128_bf16<<<(N_NODES * 64 + 255) / 256, 256, 0, stream>>>(xbhb, rs, csr, xa);
    layer_gemm<<<(N_NODES + BM - 1) / BM, 256, 0, stream>>>(
        xa, eagg, W2, b2, out, (unsigned int*)nullptr, 0, 0);
}